// Round 7
// baseline (84.055 us; speedup 1.0000x reference)
//
#include <hip/hip_runtime.h>
#include <math.h>

// Problem dims (fixed by setup_inputs)
#define B_ 4
#define G_ 8
#define D_ 8
#define H_ 256
#define W_ 320
#define N_ 9
constexpr int HW  = H_ * W_;
constexpr int DHW = D_ * HW;
constexpr int BHW = B_ * HW;
constexpr float BN_EPS = 1e-5f;

// d_ws float layout:
//   [0..127]    fw0[16][8]   (BN-folded layer0 weights)
//   [128..143]  fb0[16]      (BN-folded layer0 bias)
//   [144..271]  fw1[8][16]
//   [272..279]  fb1[8]
//   [280..287]  fw2[8]
//   [288]       fb2
//   [292..295]  sc[B]        (xnorm scale per batch)
//   [296..299]  ofs[B]       (xnorm offset per batch)
//   [320...]    pair planes: float4 plane[4][B*HW], plane j holds
//               {xn(2j), s(2j), xn(2j+1), s(2j+1)} for each pixel (21.0 MB)
#define WS_PAIR_OFF 320

// XCD band swizzle: hardware dispatches blockIdx round-robin to 8 XCDs
// (xcd = bid % 8). Remap so each XCD owns a contiguous pixel band ->
// its plane slice stays resident in its 4 MiB L2 across all 9 neighbor
// passes. nblocks must be divisible by 8.
__device__ __forceinline__ int swz_band(int bid, int per_xcd) {
    return (bid & 7) * per_xcd + (bid >> 3);
}

// ---------------- Kernel 0: fold BN into weights, precompute xnorm affine ----------------
__global__ void k_setup(
    const float* __restrict__ dmin, const float* __restrict__ dmax,
    const float* __restrict__ w0, const float* __restrict__ g0, const float* __restrict__ b0,
    const float* __restrict__ m0, const float* __restrict__ v0,
    const float* __restrict__ w1, const float* __restrict__ g1, const float* __restrict__ b1,
    const float* __restrict__ m1, const float* __restrict__ v1,
    const float* __restrict__ w2, const float* __restrict__ b2,
    float* __restrict__ ws)
{
    int t = threadIdx.x;
    if (t < 16) {
        float inv   = g0[t] * rsqrtf(v0[t] + BN_EPS);
        float shift = b0[t] - m0[t] * inv;
        for (int g = 0; g < G_; ++g) ws[t * G_ + g] = w0[t * G_ + g] * inv;
        ws[128 + t] = shift;
    }
    if (t < 8) {
        float inv   = g1[t] * rsqrtf(v1[t] + BN_EPS);
        float shift = b1[t] - m1[t] * inv;
        for (int i = 0; i < 16; ++i) ws[144 + t * 16 + i] = w1[t * 16 + i] * inv;
        ws[272 + t] = shift;
        ws[280 + t] = w2[t];
    }
    if (t == 0) ws[288] = b2[0];
    if (t < B_) {
        float imin = 1.0f / dmin[t];
        float imax = 1.0f / dmax[t];
        float sc   = 1.0f / (imin - imax);
        ws[292 + t] = sc;
        ws[296 + t] = -imax * sc;
    }
}

// ---------------- MLP for one pixel-depth: G costs -> s ----------------
__device__ __forceinline__ float mlp_eval(const float c[G_], const float* __restrict__ ws) {
    float h0[16];
#pragma unroll
    for (int o = 0; o < 16; ++o) {
        float acc = ws[128 + o];
#pragma unroll
        for (int g = 0; g < G_; ++g) acc = fmaf(c[g], ws[o * G_ + g], acc);
        h0[o] = fmaxf(acc, 0.0f);
    }
    float h1[8];
#pragma unroll
    for (int o = 0; o < 8; ++o) {
        float acc = ws[272 + o];
#pragma unroll
        for (int i = 0; i < 16; ++i) acc = fmaf(h0[i], ws[144 + o * 16 + i], acc);
        h1[o] = fmaxf(acc, 0.0f);
    }
    float s = ws[288];
#pragma unroll
    for (int i = 0; i < 8; ++i) s = fmaf(h1[i], ws[280 + i], s);
    return s;
}

// ---------------- Kernel 1: one thread per (pixel, depth-pair) ----------------
// tid = (b*HW + pix) * 4 + j, handles depths 2j and 2j+1, writes plane[j].
// 5120 blocks: XCD k covers pixels [k*40960, (k+1)*40960) — same bands as k_aggregate.
__global__ __launch_bounds__(256) void k_s_xnorm(
    const float* __restrict__ cost,      // [B,G,D,H,W]
    const float* __restrict__ dsamp,     // [B,D,H,W]
    const float* __restrict__ ws,
    float4* __restrict__ plane)          // [4][B*HW]
{
    int tid = swz_band(blockIdx.x, 640) * 256 + threadIdx.x;  // over B*HW*4
    int j   = tid & 3;
    int idx = tid >> 2;          // b*HW + pix
    int b   = idx / HW;
    int pix = idx % HW;
    int d0  = j * 2;

    float sc  = ws[292 + b];
    float ofs = ws[296 + b];

    const float* cb = cost  + (size_t)b * G_ * DHW + (size_t)d0 * HW + pix;
    const float* db = dsamp + (size_t)b * DHW + (size_t)d0 * HW + pix;

    float c0[G_], c1[G_];
#pragma unroll
    for (int g = 0; g < G_; ++g) {
        c0[g] = cb[(size_t)g * DHW];
        c1[g] = cb[(size_t)g * DHW + HW];
    }

    float s0 = mlp_eval(c0, ws);
    float s1 = mlp_eval(c1, ws);

    float4 res;
    res.x = fmaf(__builtin_amdgcn_rcpf(db[0]),  sc, ofs);
    res.y = s0;
    res.z = fmaf(__builtin_amdgcn_rcpf(db[HW]), sc, ofs);
    res.w = s1;

    plane[(size_t)j * BHW + idx] = res;
}

// ---------------- Kernel 2: neighbor gather + sigmoid kernel + aggregate ----------------
// 2 threads per pixel, split by DEPTH-PLANE (not neighbor): even lane handles
// planes j=0,1 (depths 0..3), odd lane j=2,3 (depths 4..7). Every wave
// instruction processes a single neighbor n (coherent gather streams); the
// lane pair shares identical grid/fw addresses (coalesced to one request).
// No cross-lane reduction: each thread writes its own 4 depth planes.
__global__ __launch_bounds__(256) void k_aggregate(
    const float* __restrict__ grid,      // [B, N*H, W, 2]
    const float* __restrict__ fweight,   // [B, N, H, W]
    const float4* __restrict__ plane,    // [4][B*HW]
    float* __restrict__ out)             // [B,D,H,W]
{
    int tid  = swz_band(blockIdx.x, 320) * 256 + threadIdx.x;  // over B*HW*2
    int half = tid & 1;
    int idx  = tid >> 1;          // b*HW + pix
    int b    = idx / HW;
    int pix  = idx % HW;
    int h    = pix / W_;
    int wq   = pix % W_;

    const float4* pj0 = plane + (size_t)(half * 2)     * BHW;
    const float4* pj1 = plane + (size_t)(half * 2 + 1) * BHW;

    // center xnorm for my 4 depths
    float xnc[4];
    {
        float4 v0 = pj0[idx];
        float4 v1 = pj1[idx];
        xnc[0] = v0.x; xnc[1] = v0.z;
        xnc[2] = v1.x; xnc[3] = v1.z;
    }

    float acc[4] = {0.0f, 0.0f, 0.0f, 0.0f};

    const float2* gp = (const float2*)grid;
    const int bbase = b * HW;

    for (int n = 0; n < N_; ++n) {
        float2 g = gp[(b * (N_ * H_) + n * H_ + h) * W_ + wq];
        // align_corners=False, border padding
        float gxp = fminf(fmaxf((g.x + 1.0f) * 0.5f * W_ - 0.5f, 0.0f), (float)(W_ - 1));
        float gyp = fminf(fmaxf((g.y + 1.0f) * 0.5f * H_ - 0.5f, 0.0f), (float)(H_ - 1));
        float x0f = floorf(gxp);
        float y0f = floorf(gyp);
        float wx = gxp - x0f;
        float wy = gyp - y0f;
        int x0 = (int)x0f;
        int y0 = (int)y0f;
        int x1 = min(x0 + 1, W_ - 1);
        int y1 = min(y0 + 1, H_ - 1);
        float w00 = (1.0f - wx) * (1.0f - wy);
        float w01 = wx * (1.0f - wy);
        float w10 = (1.0f - wx) * wy;
        float w11 = wx * wy;

        float fw = fweight[((b * N_ + n) * H_ + h) * W_ + wq];

        int o00 = bbase + y0 * W_ + x0;
        int o01 = bbase + y0 * W_ + x1;
        int o10 = bbase + y1 * W_ + x0;
        int o11 = bbase + y1 * W_ + x1;

        float4 a0 = pj0[o00], p0 = pj0[o01], q0 = pj0[o10], r0 = pj0[o11];
        float4 a1 = pj1[o00], p1 = pj1[o01], q1 = pj1[o10], r1 = pj1[o11];

        float xs0 = w00 * a0.x + w01 * p0.x + w10 * q0.x + w11 * r0.x;
        float ss0 = w00 * a0.y + w01 * p0.y + w10 * q0.y + w11 * r0.y;
        float xs1 = w00 * a0.z + w01 * p0.z + w10 * q0.z + w11 * r0.z;
        float ss1 = w00 * a0.w + w01 * p0.w + w10 * q0.w + w11 * r0.w;
        float xs2 = w00 * a1.x + w01 * p1.x + w10 * q1.x + w11 * r1.x;
        float ss2 = w00 * a1.y + w01 * p1.y + w10 * q1.y + w11 * r1.y;
        float xs3 = w00 * a1.z + w01 * p1.z + w10 * q1.z + w11 * r1.z;
        float ss3 = w00 * a1.w + w01 * p1.w + w10 * q1.w + w11 * r1.w;

        float df0 = fminf(fabsf(xs0 - xnc[0]) * 40.0f, 4.0f);
        float df1 = fminf(fabsf(xs1 - xnc[1]) * 40.0f, 4.0f);
        float df2 = fminf(fabsf(xs2 - xnc[2]) * 40.0f, 4.0f);
        float df3 = fminf(fabsf(xs3 - xnc[3]) * 40.0f, 4.0f);
        float dw0 = __builtin_amdgcn_rcpf(1.0f + __expf(2.0f * df0 - 4.0f));
        float dw1 = __builtin_amdgcn_rcpf(1.0f + __expf(2.0f * df1 - 4.0f));
        float dw2 = __builtin_amdgcn_rcpf(1.0f + __expf(2.0f * df2 - 4.0f));
        float dw3 = __builtin_amdgcn_rcpf(1.0f + __expf(2.0f * df3 - 4.0f));
        acc[0] = fmaf(ss0 * fw, dw0, acc[0]);
        acc[1] = fmaf(ss1 * fw, dw1, acc[1]);
        acc[2] = fmaf(ss2 * fw, dw2, acc[2]);
        acc[3] = fmaf(ss3 * fw, dw3, acc[3]);
    }

    // write my 4 depth planes (d = half*4 + dd)
    float* ob = out + ((size_t)b * D_ + half * 4) * HW + pix;
#pragma unroll
    for (int dd = 0; dd < 4; ++dd) ob[(size_t)dd * HW] = acc[dd];
}

extern "C" void kernel_launch(void* const* d_in, const int* in_sizes, int n_in,
                              void* d_out, int out_size, void* d_ws, size_t ws_size,
                              hipStream_t stream) {
    const float* cost    = (const float*)d_in[0];
    const float* dsamp   = (const float*)d_in[1];
    const float* dmin    = (const float*)d_in[2];
    const float* dmax    = (const float*)d_in[3];
    const float* grid    = (const float*)d_in[4];
    const float* fweight = (const float*)d_in[5];
    const float* w0 = (const float*)d_in[6];
    const float* g0 = (const float*)d_in[7];
    const float* b0 = (const float*)d_in[8];
    const float* m0 = (const float*)d_in[9];
    const float* v0 = (const float*)d_in[10];
    const float* w1 = (const float*)d_in[11];
    const float* g1 = (const float*)d_in[12];
    const float* b1 = (const float*)d_in[13];
    const float* m1 = (const float*)d_in[14];
    const float* v1 = (const float*)d_in[15];
    const float* w2 = (const float*)d_in[16];
    const float* b2 = (const float*)d_in[17];
    float* out = (float*)d_out;

    float*  ws    = (float*)d_ws;
    float4* plane = (float4*)(ws + WS_PAIR_OFF);

    k_setup<<<1, 64, 0, stream>>>(dmin, dmax,
                                  w0, g0, b0, m0, v0,
                                  w1, g1, b1, m1, v1,
                                  w2, b2, ws);

    // k1: 5120 blocks over (pixel, depth-pair); k2: 2560 blocks over
    // (pixel, plane-half). All kernels map pixel p -> XCD p/40960, so the
    // XCD that writes a pair band is the XCD that gathers from it.
    k_s_xnorm<<<5120, 256, 0, stream>>>(cost, dsamp, ws, plane);
    k_aggregate<<<2560, 256, 0, stream>>>(grid, fweight, plane, out);
}

// Round 8
// 82.898 us; speedup vs baseline: 1.0140x; 1.0140x over previous
//
#include <hip/hip_runtime.h>
#include <math.h>

// Problem dims (fixed by setup_inputs)
#define B_ 4
#define G_ 8
#define D_ 8
#define H_ 256
#define W_ 320
#define N_ 9
constexpr int HW  = H_ * W_;
constexpr int DHW = D_ * HW;
constexpr int BHW = B_ * HW;
constexpr float BN_EPS = 1e-5f;

// fp16 quad: {xn(2j), s(2j), xn(2j+1), s(2j+1)} for one pixel, one depth-pair.
typedef _Float16 h4v __attribute__((ext_vector_type(4)));

// d_ws float layout:
//   [0..127]    fw0[16][8]   (BN-folded layer0 weights)
//   [128..143]  fb0[16]      (BN-folded layer0 bias)
//   [144..271]  fw1[8][16]
//   [272..279]  fb1[8]
//   [280..287]  fw2[8]
//   [288]       fb2
//   [292..295]  sc[B]        (xnorm scale per batch)
//   [296..299]  ofs[B]       (xnorm offset per batch)
//   [320...]    pair planes: h4v plane[4][B*HW]  (10.5 MB total; 1.3 MB per
//               XCD band -> stays L2-resident under the grid/fw streams)
#define WS_PAIR_OFF 320

// XCD band swizzle: hardware dispatches blockIdx round-robin to 8 XCDs
// (xcd = bid % 8). Remap so each XCD owns a contiguous pixel band ->
// its plane slice stays resident in its 4 MiB L2 across all 9 neighbor
// passes. nblocks must be divisible by 8.
__device__ __forceinline__ int swz_band(int bid, int per_xcd) {
    return (bid & 7) * per_xcd + (bid >> 3);
}

// ---------------- Kernel 0: fold BN into weights, precompute xnorm affine ----------------
__global__ void k_setup(
    const float* __restrict__ dmin, const float* __restrict__ dmax,
    const float* __restrict__ w0, const float* __restrict__ g0, const float* __restrict__ b0,
    const float* __restrict__ m0, const float* __restrict__ v0,
    const float* __restrict__ w1, const float* __restrict__ g1, const float* __restrict__ b1,
    const float* __restrict__ m1, const float* __restrict__ v1,
    const float* __restrict__ w2, const float* __restrict__ b2,
    float* __restrict__ ws)
{
    int t = threadIdx.x;
    if (t < 16) {
        float inv   = g0[t] * rsqrtf(v0[t] + BN_EPS);
        float shift = b0[t] - m0[t] * inv;
        for (int g = 0; g < G_; ++g) ws[t * G_ + g] = w0[t * G_ + g] * inv;
        ws[128 + t] = shift;
    }
    if (t < 8) {
        float inv   = g1[t] * rsqrtf(v1[t] + BN_EPS);
        float shift = b1[t] - m1[t] * inv;
        for (int i = 0; i < 16; ++i) ws[144 + t * 16 + i] = w1[t * 16 + i] * inv;
        ws[272 + t] = shift;
        ws[280 + t] = w2[t];
    }
    if (t == 0) ws[288] = b2[0];
    if (t < B_) {
        float imin = 1.0f / dmin[t];
        float imax = 1.0f / dmax[t];
        float sc   = 1.0f / (imin - imax);
        ws[292 + t] = sc;
        ws[296 + t] = -imax * sc;
    }
}

// ---------------- MLP for one pixel-depth: G costs -> s ----------------
__device__ __forceinline__ float mlp_eval(const float c[G_], const float* __restrict__ ws) {
    float h0[16];
#pragma unroll
    for (int o = 0; o < 16; ++o) {
        float acc = ws[128 + o];
#pragma unroll
        for (int g = 0; g < G_; ++g) acc = fmaf(c[g], ws[o * G_ + g], acc);
        h0[o] = fmaxf(acc, 0.0f);
    }
    float h1[8];
#pragma unroll
    for (int o = 0; o < 8; ++o) {
        float acc = ws[272 + o];
#pragma unroll
        for (int i = 0; i < 16; ++i) acc = fmaf(h0[i], ws[144 + o * 16 + i], acc);
        h1[o] = fmaxf(acc, 0.0f);
    }
    float s = ws[288];
#pragma unroll
    for (int i = 0; i < 8; ++i) s = fmaf(h1[i], ws[280 + i], s);
    return s;
}

// ---------------- Kernel 1: one thread per (pixel, depth-pair) ----------------
// tid = (b*HW + pix) * 4 + j, handles depths 2j and 2j+1, writes plane[j] (fp16).
// 5120 blocks: XCD k covers pixels [k*40960, (k+1)*40960) — same bands as k_aggregate.
__global__ __launch_bounds__(256) void k_s_xnorm(
    const float* __restrict__ cost,      // [B,G,D,H,W]
    const float* __restrict__ dsamp,     // [B,D,H,W]
    const float* __restrict__ ws,
    h4v* __restrict__ plane)             // [4][B*HW]
{
    int tid = swz_band(blockIdx.x, 640) * 256 + threadIdx.x;  // over B*HW*4
    int j   = tid & 3;
    int idx = tid >> 2;          // b*HW + pix
    int b   = idx / HW;
    int pix = idx % HW;
    int d0  = j * 2;

    float sc  = ws[292 + b];
    float ofs = ws[296 + b];

    const float* cb = cost  + (size_t)b * G_ * DHW + (size_t)d0 * HW + pix;
    const float* db = dsamp + (size_t)b * DHW + (size_t)d0 * HW + pix;

    float c0[G_], c1[G_];
#pragma unroll
    for (int g = 0; g < G_; ++g) {
        c0[g] = cb[(size_t)g * DHW];
        c1[g] = cb[(size_t)g * DHW + HW];
    }

    float s0 = mlp_eval(c0, ws);
    float s1 = mlp_eval(c1, ws);

    float xn0 = fmaf(__builtin_amdgcn_rcpf(db[0]),  sc, ofs);
    float xn1 = fmaf(__builtin_amdgcn_rcpf(db[HW]), sc, ofs);

    h4v res;
    res[0] = (_Float16)xn0;
    res[1] = (_Float16)s0;
    res[2] = (_Float16)xn1;
    res[3] = (_Float16)s1;

    plane[(size_t)j * BHW + idx] = res;
}

// ---------------- Kernel 2: neighbor gather + sigmoid kernel + aggregate ----------------
// 2 threads per pixel, split by depth-plane: even lane handles planes j=0,1
// (depths 0..3), odd lane j=2,3 (depths 4..7). Taps are 8-byte fp16 quads;
// interpolation in fp32 after convert. Each thread writes its own 4 depth planes.
__global__ __launch_bounds__(256) void k_aggregate(
    const float* __restrict__ grid,      // [B, N*H, W, 2]
    const float* __restrict__ fweight,   // [B, N, H, W]
    const h4v* __restrict__ plane,       // [4][B*HW]
    float* __restrict__ out)             // [B,D,H,W]
{
    int tid  = swz_band(blockIdx.x, 320) * 256 + threadIdx.x;  // over B*HW*2
    int half = tid & 1;
    int idx  = tid >> 1;          // b*HW + pix
    int b    = idx / HW;
    int pix  = idx % HW;
    int h    = pix / W_;
    int wq   = pix % W_;

    const h4v* pj0 = plane + (size_t)(half * 2)     * BHW;
    const h4v* pj1 = plane + (size_t)(half * 2 + 1) * BHW;

    // center xnorm for my 4 depths (fp16-rounded, same as taps)
    float xnc0, xnc1, xnc2, xnc3;
    {
        h4v v0 = pj0[idx];
        h4v v1 = pj1[idx];
        xnc0 = (float)v0[0]; xnc1 = (float)v0[2];
        xnc2 = (float)v1[0]; xnc3 = (float)v1[2];
    }

    float acc[4] = {0.0f, 0.0f, 0.0f, 0.0f};

    const float2* gp = (const float2*)grid;
    const int bbase = b * HW;

    for (int n = 0; n < N_; ++n) {
        float2 g = gp[(b * (N_ * H_) + n * H_ + h) * W_ + wq];
        // align_corners=False, border padding
        float gxp = fminf(fmaxf((g.x + 1.0f) * 0.5f * W_ - 0.5f, 0.0f), (float)(W_ - 1));
        float gyp = fminf(fmaxf((g.y + 1.0f) * 0.5f * H_ - 0.5f, 0.0f), (float)(H_ - 1));
        float x0f = floorf(gxp);
        float y0f = floorf(gyp);
        float wx = gxp - x0f;
        float wy = gyp - y0f;
        int x0 = (int)x0f;
        int y0 = (int)y0f;
        int x1 = min(x0 + 1, W_ - 1);
        int y1 = min(y0 + 1, H_ - 1);
        float w00 = (1.0f - wx) * (1.0f - wy);
        float w01 = wx * (1.0f - wy);
        float w10 = (1.0f - wx) * wy;
        float w11 = wx * wy;

        float fw = fweight[((b * N_ + n) * H_ + h) * W_ + wq];

        int o00 = bbase + y0 * W_ + x0;
        int o01 = bbase + y0 * W_ + x1;
        int o10 = bbase + y1 * W_ + x0;
        int o11 = bbase + y1 * W_ + x1;

        h4v a0 = pj0[o00], p0 = pj0[o01], q0 = pj0[o10], r0 = pj0[o11];
        h4v a1 = pj1[o00], p1 = pj1[o01], q1 = pj1[o10], r1 = pj1[o11];

        float xs0 = w00 * (float)a0[0] + w01 * (float)p0[0] + w10 * (float)q0[0] + w11 * (float)r0[0];
        float ss0 = w00 * (float)a0[1] + w01 * (float)p0[1] + w10 * (float)q0[1] + w11 * (float)r0[1];
        float xs1 = w00 * (float)a0[2] + w01 * (float)p0[2] + w10 * (float)q0[2] + w11 * (float)r0[2];
        float ss1 = w00 * (float)a0[3] + w01 * (float)p0[3] + w10 * (float)q0[3] + w11 * (float)r0[3];
        float xs2 = w00 * (float)a1[0] + w01 * (float)p1[0] + w10 * (float)q1[0] + w11 * (float)r1[0];
        float ss2 = w00 * (float)a1[1] + w01 * (float)p1[1] + w10 * (float)q1[1] + w11 * (float)r1[1];
        float xs3 = w00 * (float)a1[2] + w01 * (float)p1[2] + w10 * (float)q1[2] + w11 * (float)r1[2];
        float ss3 = w00 * (float)a1[3] + w01 * (float)p1[3] + w10 * (float)q1[3] + w11 * (float)r1[3];

        float df0 = fminf(fabsf(xs0 - xnc0) * 40.0f, 4.0f);
        float df1 = fminf(fabsf(xs1 - xnc1) * 40.0f, 4.0f);
        float df2 = fminf(fabsf(xs2 - xnc2) * 40.0f, 4.0f);
        float df3 = fminf(fabsf(xs3 - xnc3) * 40.0f, 4.0f);
        float dw0 = __builtin_amdgcn_rcpf(1.0f + __expf(2.0f * df0 - 4.0f));
        float dw1 = __builtin_amdgcn_rcpf(1.0f + __expf(2.0f * df1 - 4.0f));
        float dw2 = __builtin_amdgcn_rcpf(1.0f + __expf(2.0f * df2 - 4.0f));
        float dw3 = __builtin_amdgcn_rcpf(1.0f + __expf(2.0f * df3 - 4.0f));
        acc[0] = fmaf(ss0 * fw, dw0, acc[0]);
        acc[1] = fmaf(ss1 * fw, dw1, acc[1]);
        acc[2] = fmaf(ss2 * fw, dw2, acc[2]);
        acc[3] = fmaf(ss3 * fw, dw3, acc[3]);
    }

    // write my 4 depth planes (d = half*4 + dd)
    float* ob = out + ((size_t)b * D_ + half * 4) * HW + pix;
#pragma unroll
    for (int dd = 0; dd < 4; ++dd) ob[(size_t)dd * HW] = acc[dd];
}

extern "C" void kernel_launch(void* const* d_in, const int* in_sizes, int n_in,
                              void* d_out, int out_size, void* d_ws, size_t ws_size,
                              hipStream_t stream) {
    const float* cost    = (const float*)d_in[0];
    const float* dsamp   = (const float*)d_in[1];
    const float* dmin    = (const float*)d_in[2];
    const float* dmax    = (const float*)d_in[3];
    const float* grid    = (const float*)d_in[4];
    const float* fweight = (const float*)d_in[5];
    const float* w0 = (const float*)d_in[6];
    const float* g0 = (const float*)d_in[7];
    const float* b0 = (const float*)d_in[8];
    const float* m0 = (const float*)d_in[9];
    const float* v0 = (const float*)d_in[10];
    const float* w1 = (const float*)d_in[11];
    const float* g1 = (const float*)d_in[12];
    const float* b1 = (const float*)d_in[13];
    const float* m1 = (const float*)d_in[14];
    const float* v1 = (const float*)d_in[15];
    const float* w2 = (const float*)d_in[16];
    const float* b2 = (const float*)d_in[17];
    float* out = (float*)d_out;

    float* ws    = (float*)d_ws;
    h4v*   plane = (h4v*)(ws + WS_PAIR_OFF);

    k_setup<<<1, 64, 0, stream>>>(dmin, dmax,
                                  w0, g0, b0, m0, v0,
                                  w1, g1, b1, m1, v1,
                                  w2, b2, ws);

    // k1: 5120 blocks over (pixel, depth-pair); k2: 2560 blocks over
    // (pixel, plane-half). All kernels map pixel p -> XCD p/40960, so the
    // XCD that writes a pair band is the XCD that gathers from it.
    k_s_xnorm<<<5120, 256, 0, stream>>>(cost, dsamp, ws, plane);
    k_aggregate<<<2560, 256, 0, stream>>>(grid, fweight, plane, out);
}

// Round 9
// 82.773 us; speedup vs baseline: 1.0155x; 1.0015x over previous
//
#include <hip/hip_runtime.h>
#include <math.h>

// Problem dims (fixed by setup_inputs)
#define B_ 4
#define G_ 8
#define D_ 8
#define H_ 256
#define W_ 320
#define N_ 9
constexpr int HW  = H_ * W_;
constexpr int DHW = D_ * HW;
constexpr int BHW = B_ * HW;
constexpr float BN_EPS = 1e-5f;

// fp16 quad: {xn(2j), s(2j), xn(2j+1), s(2j+1)} for one pixel, one depth-pair.
typedef _Float16 h4v __attribute__((ext_vector_type(4)));
// two adjacent pixels' quads (16 B): [0..3] = pixel x0, [4..7] = pixel x0+1
typedef _Float16 h8v __attribute__((ext_vector_type(8)));

// d_ws float layout:
//   [0..127]    fw0[16][8]   (BN-folded layer0 weights)
//   [128..143]  fb0[16]      (BN-folded layer0 bias)
//   [144..271]  fw1[8][16]
//   [272..279]  fb1[8]
//   [280..287]  fw2[8]
//   [288]       fb2
//   [292..295]  sc[B]        (xnorm scale per batch)
//   [296..299]  ofs[B]       (xnorm offset per batch)
//   [320...]    pair planes: h4v plane[4][B*HW]  (10.5 MB)
#define WS_PAIR_OFF 320

// XCD band swizzle (see round 2): each XCD owns a contiguous pixel band so
// its plane slice stays L2-resident across all 9 neighbor passes.
__device__ __forceinline__ int swz_band(int bid, int per_xcd) {
    return (bid & 7) * per_xcd + (bid >> 3);
}

// ---------------- Kernel 0: fold BN into weights, precompute xnorm affine ----------------
__global__ void k_setup(
    const float* __restrict__ dmin, const float* __restrict__ dmax,
    const float* __restrict__ w0, const float* __restrict__ g0, const float* __restrict__ b0,
    const float* __restrict__ m0, const float* __restrict__ v0,
    const float* __restrict__ w1, const float* __restrict__ g1, const float* __restrict__ b1,
    const float* __restrict__ m1, const float* __restrict__ v1,
    const float* __restrict__ w2, const float* __restrict__ b2,
    float* __restrict__ ws)
{
    int t = threadIdx.x;
    if (t < 16) {
        float inv   = g0[t] * rsqrtf(v0[t] + BN_EPS);
        float shift = b0[t] - m0[t] * inv;
        for (int g = 0; g < G_; ++g) ws[t * G_ + g] = w0[t * G_ + g] * inv;
        ws[128 + t] = shift;
    }
    if (t < 8) {
        float inv   = g1[t] * rsqrtf(v1[t] + BN_EPS);
        float shift = b1[t] - m1[t] * inv;
        for (int i = 0; i < 16; ++i) ws[144 + t * 16 + i] = w1[t * 16 + i] * inv;
        ws[272 + t] = shift;
        ws[280 + t] = w2[t];
    }
    if (t == 0) ws[288] = b2[0];
    if (t < B_) {
        float imin = 1.0f / dmin[t];
        float imax = 1.0f / dmax[t];
        float sc   = 1.0f / (imin - imax);
        ws[292 + t] = sc;
        ws[296 + t] = -imax * sc;
    }
}

// ---------------- MLP for one pixel-depth: G costs -> s ----------------
__device__ __forceinline__ float mlp_eval(const float c[G_], const float* __restrict__ ws) {
    float h0[16];
#pragma unroll
    for (int o = 0; o < 16; ++o) {
        float acc = ws[128 + o];
#pragma unroll
        for (int g = 0; g < G_; ++g) acc = fmaf(c[g], ws[o * G_ + g], acc);
        h0[o] = fmaxf(acc, 0.0f);
    }
    float h1[8];
#pragma unroll
    for (int o = 0; o < 8; ++o) {
        float acc = ws[272 + o];
#pragma unroll
        for (int i = 0; i < 16; ++i) acc = fmaf(h0[i], ws[144 + o * 16 + i], acc);
        h1[o] = fmaxf(acc, 0.0f);
    }
    float s = ws[288];
#pragma unroll
    for (int i = 0; i < 8; ++i) s = fmaf(h1[i], ws[280 + i], s);
    return s;
}

// ---------------- Kernel 1: one thread per (pixel, depth-pair) ----------------
__global__ __launch_bounds__(256) void k_s_xnorm(
    const float* __restrict__ cost,      // [B,G,D,H,W]
    const float* __restrict__ dsamp,     // [B,D,H,W]
    const float* __restrict__ ws,
    h4v* __restrict__ plane)             // [4][B*HW]
{
    int tid = swz_band(blockIdx.x, 640) * 256 + threadIdx.x;  // over B*HW*4
    int j   = tid & 3;
    int idx = tid >> 2;          // b*HW + pix
    int b   = idx / HW;
    int pix = idx % HW;
    int d0  = j * 2;

    float sc  = ws[292 + b];
    float ofs = ws[296 + b];

    const float* cb = cost  + (size_t)b * G_ * DHW + (size_t)d0 * HW + pix;
    const float* db = dsamp + (size_t)b * DHW + (size_t)d0 * HW + pix;

    float c0[G_], c1[G_];
#pragma unroll
    for (int g = 0; g < G_; ++g) {
        c0[g] = cb[(size_t)g * DHW];
        c1[g] = cb[(size_t)g * DHW + HW];
    }

    float s0 = mlp_eval(c0, ws);
    float s1 = mlp_eval(c1, ws);

    float xn0 = fmaf(__builtin_amdgcn_rcpf(db[0]),  sc, ofs);
    float xn1 = fmaf(__builtin_amdgcn_rcpf(db[HW]), sc, ofs);

    h4v res;
    res[0] = (_Float16)xn0;
    res[1] = (_Float16)s0;
    res[2] = (_Float16)xn1;
    res[3] = (_Float16)s1;

    plane[(size_t)j * BHW + idx] = res;
}

// ---------------- Kernel 2: neighbor gather + sigmoid kernel + aggregate ----------------
// 1 thread per pixel, all 8 depths. Per neighbor per plane: ONE 16B load
// covers both x-taps of a row (x0, x0+1 are contiguous 8B quads) -> 2 loads
// per plane (rows y0,y1), 8 tap loads + grid + fw = 10 VMEM per neighbor.
// Border: x0==W-1 implies wx==0 exactly, so the out-of-row second quad gets
// zero weight (memory stays in-bounds within d_ws).
__global__ __launch_bounds__(256) void k_aggregate(
    const float* __restrict__ grid,      // [B, N*H, W, 2]
    const float* __restrict__ fweight,   // [B, N, H, W]
    const h4v* __restrict__ plane,       // [4][B*HW]
    float* __restrict__ out)             // [B,D,H,W]
{
    int idx = swz_band(blockIdx.x, 160) * 256 + threadIdx.x;  // b*HW + pix
    int b   = idx / HW;
    int pix = idx % HW;
    int h   = pix / W_;
    int wq  = pix % W_;

    // ---- prefetch grid + fw for all neighbors (independent loads) ----
    const float2* gp = (const float2*)grid;
    float2 gv[N_];
    float  fwv[N_];
#pragma unroll
    for (int n = 0; n < N_; ++n) {
        gv[n]  = gp[(b * (N_ * H_) + n * H_ + h) * W_ + wq];
        fwv[n] = fweight[((b * N_ + n) * H_ + h) * W_ + wq];
    }

    // ---- center xnorm per depth ----
    float xnc[D_];
#pragma unroll
    for (int j = 0; j < 4; ++j) {
        h4v v = plane[(size_t)j * BHW + idx];
        xnc[2 * j]     = (float)v[0];
        xnc[2 * j + 1] = (float)v[2];
    }

    float acc[D_];
#pragma unroll
    for (int d = 0; d < D_; ++d) acc[d] = 0.0f;

    const int bbase = b * HW;

    for (int n = 0; n < N_; ++n) {
        // align_corners=False, border padding
        float gxp = fminf(fmaxf((gv[n].x + 1.0f) * 0.5f * W_ - 0.5f, 0.0f), (float)(W_ - 1));
        float gyp = fminf(fmaxf((gv[n].y + 1.0f) * 0.5f * H_ - 0.5f, 0.0f), (float)(H_ - 1));
        float x0f = floorf(gxp);
        float y0f = floorf(gyp);
        float wx = gxp - x0f;          // == 0 exactly when x0 == W-1 (clamped)
        float wy = gyp - y0f;
        int x0 = (int)x0f;
        int y0 = (int)y0f;
        int y1 = min(y0 + 1, H_ - 1);
        float fw = fwv[n];

        int oA = bbase + y0 * W_ + x0;  // row y0, pixels x0 & x0+1 via one 16B load
        int oB = bbase + y1 * W_ + x0;  // row y1

#pragma unroll
        for (int j = 0; j < 4; ++j) {
            const h4v* pj = plane + (size_t)j * BHW;
            h8v rA = *(const h8v*)(pj + oA);
            h8v rB = *(const h8v*)(pj + oB);

            // x-lerp then y-lerp, all in fp32
            float t0 = (float)rA[0], t1 = (float)rA[1], t2 = (float)rA[2], t3 = (float)rA[3];
            float u0 = (float)rA[4], u1 = (float)rA[5], u2 = (float)rA[6], u3 = (float)rA[7];
            float a0 = fmaf(wx, u0 - t0, t0);
            float a1 = fmaf(wx, u1 - t1, t1);
            float a2 = fmaf(wx, u2 - t2, t2);
            float a3 = fmaf(wx, u3 - t3, t3);

            float v0 = (float)rB[0], v1 = (float)rB[1], v2 = (float)rB[2], v3 = (float)rB[3];
            float z0 = (float)rB[4], z1 = (float)rB[5], z2 = (float)rB[6], z3 = (float)rB[7];
            float b0 = fmaf(wx, z0 - v0, v0);
            float b1 = fmaf(wx, z1 - v1, v1);
            float b2 = fmaf(wx, z2 - v2, v2);
            float b3 = fmaf(wx, z3 - v3, v3);

            float xs0 = fmaf(wy, b0 - a0, a0);
            float ss0 = fmaf(wy, b1 - a1, a1);
            float xs1 = fmaf(wy, b2 - a2, a2);
            float ss1 = fmaf(wy, b3 - a3, a3);

            float df0 = fminf(fabsf(xs0 - xnc[2 * j]) * 40.0f, 4.0f);
            float df1 = fminf(fabsf(xs1 - xnc[2 * j + 1]) * 40.0f, 4.0f);
            float dw0 = __builtin_amdgcn_rcpf(1.0f + __expf(2.0f * df0 - 4.0f));
            float dw1 = __builtin_amdgcn_rcpf(1.0f + __expf(2.0f * df1 - 4.0f));
            acc[2 * j]     = fmaf(ss0 * fw, dw0, acc[2 * j]);
            acc[2 * j + 1] = fmaf(ss1 * fw, dw1, acc[2 * j + 1]);
        }
    }

#pragma unroll
    for (int d = 0; d < D_; ++d) out[(b * D_ + d) * HW + pix] = acc[d];
}

extern "C" void kernel_launch(void* const* d_in, const int* in_sizes, int n_in,
                              void* d_out, int out_size, void* d_ws, size_t ws_size,
                              hipStream_t stream) {
    const float* cost    = (const float*)d_in[0];
    const float* dsamp   = (const float*)d_in[1];
    const float* dmin    = (const float*)d_in[2];
    const float* dmax    = (const float*)d_in[3];
    const float* grid    = (const float*)d_in[4];
    const float* fweight = (const float*)d_in[5];
    const float* w0 = (const float*)d_in[6];
    const float* g0 = (const float*)d_in[7];
    const float* b0 = (const float*)d_in[8];
    const float* m0 = (const float*)d_in[9];
    const float* v0 = (const float*)d_in[10];
    const float* w1 = (const float*)d_in[11];
    const float* g1 = (const float*)d_in[12];
    const float* b1 = (const float*)d_in[13];
    const float* m1 = (const float*)d_in[14];
    const float* v1 = (const float*)d_in[15];
    const float* w2 = (const float*)d_in[16];
    const float* b2 = (const float*)d_in[17];
    float* out = (float*)d_out;

    float* ws    = (float*)d_ws;
    h4v*   plane = (h4v*)(ws + WS_PAIR_OFF);

    k_setup<<<1, 64, 0, stream>>>(dmin, dmax,
                                  w0, g0, b0, m0, v0,
                                  w1, g1, b1, m1, v1,
                                  w2, b2, ws);

    // k1: 5120 blocks over (pixel, depth-pair); k2: 1280 blocks over pixels.
    // Both map pixel p -> XCD p/40960 (producer/consumer L2 affinity).
    k_s_xnorm<<<5120, 256, 0, stream>>>(cost, dsamp, ws, plane);
    k_aggregate<<<1280, 256, 0, stream>>>(grid, fweight, plane, out);
}

// Round 10
// 60.234 us; speedup vs baseline: 1.3955x; 1.3742x over previous
//
#include <hip/hip_runtime.h>
#include <math.h>

// Problem dims (fixed by setup_inputs)
#define B_ 4
#define G_ 8
#define D_ 8
#define H_ 256
#define W_ 320
#define N_ 9
constexpr int HW  = H_ * W_;
constexpr int DHW = D_ * HW;
constexpr int BHW = B_ * HW;
constexpr float BN_EPS = 1e-5f;

// fp16 quad: {xn(2j), s(2j), xn(2j+1), s(2j+1)} for one pixel, one depth-pair.
typedef _Float16 h4v __attribute__((ext_vector_type(4)));
// two adjacent pixels' quads (16 B): [0..3] = pixel x0, [4..7] = pixel x0+1
typedef _Float16 h8v __attribute__((ext_vector_type(8)));

// d_ws float layout:
//   [0..127]    fw0[16][8]   (BN-folded layer0 weights)
//   [128..143]  fb0[16]      (BN-folded layer0 bias)
//   [144..271]  fw1[8][16]
//   [272..279]  fb1[8]
//   [280..287]  fw2[8]
//   [288]       fb2
//   [292..295]  sc[B]        (xnorm scale per batch)
//   [296..299]  ofs[B]       (xnorm offset per batch)
//   [320...]    pair planes: h4v plane[4][B*HW]  (10.5 MB)
#define WS_PAIR_OFF 320

// XCD band swizzle (see round 2): each XCD owns a contiguous pixel band so
// its plane slice stays L2-resident across all 9 neighbor passes.
__device__ __forceinline__ int swz_band(int bid, int per_xcd) {
    return (bid & 7) * per_xcd + (bid >> 3);
}

// ---------------- Kernel 0: fold BN into weights, precompute xnorm affine ----------------
__global__ void k_setup(
    const float* __restrict__ dmin, const float* __restrict__ dmax,
    const float* __restrict__ w0, const float* __restrict__ g0, const float* __restrict__ b0,
    const float* __restrict__ m0, const float* __restrict__ v0,
    const float* __restrict__ w1, const float* __restrict__ g1, const float* __restrict__ b1,
    const float* __restrict__ m1, const float* __restrict__ v1,
    const float* __restrict__ w2, const float* __restrict__ b2,
    float* __restrict__ ws)
{
    int t = threadIdx.x;
    if (t < 16) {
        float inv   = g0[t] * rsqrtf(v0[t] + BN_EPS);
        float shift = b0[t] - m0[t] * inv;
        for (int g = 0; g < G_; ++g) ws[t * G_ + g] = w0[t * G_ + g] * inv;
        ws[128 + t] = shift;
    }
    if (t < 8) {
        float inv   = g1[t] * rsqrtf(v1[t] + BN_EPS);
        float shift = b1[t] - m1[t] * inv;
        for (int i = 0; i < 16; ++i) ws[144 + t * 16 + i] = w1[t * 16 + i] * inv;
        ws[272 + t] = shift;
        ws[280 + t] = w2[t];
    }
    if (t == 0) ws[288] = b2[0];
    if (t < B_) {
        float imin = 1.0f / dmin[t];
        float imax = 1.0f / dmax[t];
        float sc   = 1.0f / (imin - imax);
        ws[292 + t] = sc;
        ws[296 + t] = -imax * sc;
    }
}

// ---------------- MLP for one pixel-depth: G costs -> s ----------------
__device__ __forceinline__ float mlp_eval(const float c[G_], const float* __restrict__ ws) {
    float h0[16];
#pragma unroll
    for (int o = 0; o < 16; ++o) {
        float acc = ws[128 + o];
#pragma unroll
        for (int g = 0; g < G_; ++g) acc = fmaf(c[g], ws[o * G_ + g], acc);
        h0[o] = fmaxf(acc, 0.0f);
    }
    float h1[8];
#pragma unroll
    for (int o = 0; o < 8; ++o) {
        float acc = ws[272 + o];
#pragma unroll
        for (int i = 0; i < 16; ++i) acc = fmaf(h0[i], ws[144 + o * 16 + i], acc);
        h1[o] = fmaxf(acc, 0.0f);
    }
    float s = ws[288];
#pragma unroll
    for (int i = 0; i < 8; ++i) s = fmaf(h1[i], ws[280 + i], s);
    return s;
}

// ---------------- Kernel 1: one thread per (pixel, depth-pair) ----------------
__global__ __launch_bounds__(256) void k_s_xnorm(
    const float* __restrict__ cost,      // [B,G,D,H,W]
    const float* __restrict__ dsamp,     // [B,D,H,W]
    const float* __restrict__ ws,
    h4v* __restrict__ plane)             // [4][B*HW]
{
    int tid = swz_band(blockIdx.x, 640) * 256 + threadIdx.x;  // over B*HW*4
    int j   = tid & 3;
    int idx = tid >> 2;          // b*HW + pix
    int b   = idx / HW;
    int pix = idx % HW;
    int d0  = j * 2;

    float sc  = ws[292 + b];
    float ofs = ws[296 + b];

    const float* cb = cost  + (size_t)b * G_ * DHW + (size_t)d0 * HW + pix;
    const float* db = dsamp + (size_t)b * DHW + (size_t)d0 * HW + pix;

    float c0[G_], c1[G_];
#pragma unroll
    for (int g = 0; g < G_; ++g) {
        c0[g] = cb[(size_t)g * DHW];
        c1[g] = cb[(size_t)g * DHW + HW];
    }

    float s0 = mlp_eval(c0, ws);
    float s1 = mlp_eval(c1, ws);

    float xn0 = fmaf(__builtin_amdgcn_rcpf(db[0]),  sc, ofs);
    float xn1 = fmaf(__builtin_amdgcn_rcpf(db[HW]), sc, ofs);

    h4v res;
    res[0] = (_Float16)xn0;
    res[1] = (_Float16)s0;
    res[2] = (_Float16)xn1;
    res[3] = (_Float16)s1;

    plane[(size_t)j * BHW + idx] = res;
}

// ---------------- Kernel 2: neighbor gather + sigmoid kernel + aggregate ----------------
// 1 thread per pixel, all 8 depths. FULLY UNROLLED over the 9 neighbors:
// every grid/fw/tap load is an independent SSA value, so the compiler can
// keep many loads in flight (vmcnt batching) instead of serializing one
// ~250-cycle L2 round-trip per neighbor. No arrays -> no LDS scratch.
// Per neighbor per plane: ONE 16B load covers both x-taps of a row.
__global__ __launch_bounds__(256) void k_aggregate(
    const float* __restrict__ grid,      // [B, N*H, W, 2]
    const float* __restrict__ fweight,   // [B, N, H, W]
    const h4v* __restrict__ plane,       // [4][B*HW]
    float* __restrict__ out)             // [B,D,H,W]
{
    int idx = swz_band(blockIdx.x, 160) * 256 + threadIdx.x;  // b*HW + pix
    int b   = idx / HW;
    int pix = idx % HW;
    int h   = pix / W_;
    int wq  = pix % W_;

    const float2* gpx = (const float2*)grid + (size_t)b * (N_ * H_) * W_ + (size_t)h * W_ + wq;
    const float*  fpx = fweight + (size_t)b * N_ * HW + (size_t)h * W_ + wq;

    // ---- center xnorm per depth ----
    float xnc[D_];
#pragma unroll
    for (int j = 0; j < 4; ++j) {
        h4v v = plane[(size_t)j * BHW + idx];
        xnc[2 * j]     = (float)v[0];
        xnc[2 * j + 1] = (float)v[2];
    }

    float acc[D_];
#pragma unroll
    for (int d = 0; d < D_; ++d) acc[d] = 0.0f;

    const int bbase = b * HW;

#pragma unroll
    for (int n = 0; n < N_; ++n) {
        float2 g  = gpx[(size_t)n * (H_ * W_)];
        float  fw = fpx[(size_t)n * HW];

        // align_corners=False, border padding
        float gxp = fminf(fmaxf((g.x + 1.0f) * 0.5f * W_ - 0.5f, 0.0f), (float)(W_ - 1));
        float gyp = fminf(fmaxf((g.y + 1.0f) * 0.5f * H_ - 0.5f, 0.0f), (float)(H_ - 1));
        float x0f = floorf(gxp);
        float y0f = floorf(gyp);
        float wx = gxp - x0f;          // == 0 exactly when x0 == W-1 (clamped)
        float wy = gyp - y0f;
        int x0 = (int)x0f;
        int y0 = (int)y0f;
        int y1 = min(y0 + 1, H_ - 1);

        int oA = bbase + y0 * W_ + x0;  // row y0: pixels x0 & x0+1 via one 16B load
        int oB = bbase + y1 * W_ + x0;  // row y1

#pragma unroll
        for (int j = 0; j < 4; ++j) {
            const h4v* pj = plane + (size_t)j * BHW;
            h8v rA = *(const h8v*)(pj + oA);
            h8v rB = *(const h8v*)(pj + oB);

            // x-lerp then y-lerp, all in fp32
            float t0 = (float)rA[0], t1 = (float)rA[1], t2 = (float)rA[2], t3 = (float)rA[3];
            float u0 = (float)rA[4], u1 = (float)rA[5], u2 = (float)rA[6], u3 = (float)rA[7];
            float a0 = fmaf(wx, u0 - t0, t0);
            float a1 = fmaf(wx, u1 - t1, t1);
            float a2 = fmaf(wx, u2 - t2, t2);
            float a3 = fmaf(wx, u3 - t3, t3);

            float v0 = (float)rB[0], v1 = (float)rB[1], v2 = (float)rB[2], v3 = (float)rB[3];
            float z0 = (float)rB[4], z1 = (float)rB[5], z2 = (float)rB[6], z3 = (float)rB[7];
            float b0 = fmaf(wx, z0 - v0, v0);
            float b1 = fmaf(wx, z1 - v1, v1);
            float b2 = fmaf(wx, z2 - v2, v2);
            float b3 = fmaf(wx, z3 - v3, v3);

            float xs0 = fmaf(wy, b0 - a0, a0);
            float ss0 = fmaf(wy, b1 - a1, a1);
            float xs1 = fmaf(wy, b2 - a2, a2);
            float ss1 = fmaf(wy, b3 - a3, a3);

            float df0 = fminf(fabsf(xs0 - xnc[2 * j]) * 40.0f, 4.0f);
            float df1 = fminf(fabsf(xs1 - xnc[2 * j + 1]) * 40.0f, 4.0f);
            float dw0 = __builtin_amdgcn_rcpf(1.0f + __expf(2.0f * df0 - 4.0f));
            float dw1 = __builtin_amdgcn_rcpf(1.0f + __expf(2.0f * df1 - 4.0f));
            acc[2 * j]     = fmaf(ss0 * fw, dw0, acc[2 * j]);
            acc[2 * j + 1] = fmaf(ss1 * fw, dw1, acc[2 * j + 1]);
        }
    }

#pragma unroll
    for (int d = 0; d < D_; ++d) out[(b * D_ + d) * HW + pix] = acc[d];
}

extern "C" void kernel_launch(void* const* d_in, const int* in_sizes, int n_in,
                              void* d_out, int out_size, void* d_ws, size_t ws_size,
                              hipStream_t stream) {
    const float* cost    = (const float*)d_in[0];
    const float* dsamp   = (const float*)d_in[1];
    const float* dmin    = (const float*)d_in[2];
    const float* dmax    = (const float*)d_in[3];
    const float* grid    = (const float*)d_in[4];
    const float* fweight = (const float*)d_in[5];
    const float* w0 = (const float*)d_in[6];
    const float* g0 = (const float*)d_in[7];
    const float* b0 = (const float*)d_in[8];
    const float* m0 = (const float*)d_in[9];
    const float* v0 = (const float*)d_in[10];
    const float* w1 = (const float*)d_in[11];
    const float* g1 = (const float*)d_in[12];
    const float* b1 = (const float*)d_in[13];
    const float* m1 = (const float*)d_in[14];
    const float* v1 = (const float*)d_in[15];
    const float* w2 = (const float*)d_in[16];
    const float* b2 = (const float*)d_in[17];
    float* out = (float*)d_out;

    float* ws    = (float*)d_ws;
    h4v*   plane = (h4v*)(ws + WS_PAIR_OFF);

    k_setup<<<1, 64, 0, stream>>>(dmin, dmax,
                                  w0, g0, b0, m0, v0,
                                  w1, g1, b1, m1, v1,
                                  w2, b2, ws);

    // k1: 5120 blocks over (pixel, depth-pair); k2: 1280 blocks over pixels.
    // Both map pixel p -> XCD p/40960 (producer/consumer L2 affinity).
    k_s_xnorm<<<5120, 256, 0, stream>>>(cost, dsamp, ws, plane);
    k_aggregate<<<1280, 256, 0, stream>>>(grid, fweight, plane, out);
}